// Round 1
// baseline (4466.474 us; speedup 1.0000x reference)
//
#include <hip/hip_runtime.h>
#include <hip/hip_bf16.h>

#define B_ 256
#define T_ 256
#define I_ 5
#define H_ 2048
#define O_ 4

typedef __attribute__((ext_vector_type(8))) short bf16x8;
typedef __attribute__((ext_vector_type(4))) float f32x4;

__device__ __forceinline__ unsigned short f2bf(float f) {
    __hip_bfloat16 h = __float2bfloat16(f);
    unsigned short r;
    __builtin_memcpy(&r, &h, 2);
    return r;
}

// Swizzle Wrec fp32 [H][H] row-major -> bf16 MFMA-B fragment tile layout.
// Tile (ut, kt): rows u in [ut*16,..+16), k in [kt*32,..+32).
// Lane ((k%32)/8)*16 + (u%16) holds 8 contiguous bf16 (k%8 = 0..7) => 16B/lane.
__global__ __launch_bounds__(256) void swizzle_W(const float* __restrict__ Wrec,
                                                 unsigned short* __restrict__ Wt) {
    int tid = blockIdx.x * 256 + threadIdx.x;   // H * (H/8) threads
    int u = tid >> 8;                           // H_/8 = 256 chunks per row
    int k0 = (tid & 255) << 3;
    const float* src = Wrec + u * H_ + k0;
    int ut = u >> 4;
    int kt = k0 >> 5;
    int lane = (((k0 >> 3) & 3) << 4) + (u & 15);
    unsigned short* dst = Wt + ((((ut << 6) + kt) << 6) + lane) * 8;
#pragma unroll
    for (int j = 0; j < 8; ++j) dst[j] = f2bf(src[j]);
}

// One recurrence step. Grid (32, 8), 256 threads (4 waves).
// Block covers 32 batches (blockIdx.y*32) x 64 units (blockIdx.x*64).
// Wave w: b-subtile = w&1 (16 b), u-half = w>>1 (2 u-tiles of 16).
__global__ __launch_bounds__(256) void step_kernel(
    const unsigned short* __restrict__ Wt,     // bf16 B-frag tiles
    const unsigned short* __restrict__ hsrc,   // bf16 A-frag tiles (state t-1)
    unsigned short* __restrict__ hdst,         // bf16 A-frag tiles (state t)
    float* __restrict__ hstate,                // fp32 [B][H] state
    const float* __restrict__ x,               // [B][T][I]
    const float* __restrict__ Win,             // [H][I]
    const float* __restrict__ noise,           // [T][B][H]
    float* __restrict__ hid_out,               // d_out hiddens [B][T][H]
    int t)
{
    const int lane = threadIdx.x & 63;
    const int w = threadIdx.x >> 6;
    const int bt = blockIdx.y * 2 + (w & 1);            // A tile (16 b)
    const int ut0 = blockIdx.x * 4 + ((w >> 1) << 1);   // first of 2 u tiles

    const bf16x8* Ap  = (const bf16x8*)hsrc + (bt << 6) * 64 + lane;
    const bf16x8* Bp0 = (const bf16x8*)Wt + (ut0 << 6) * 64 + lane;
    const bf16x8* Bp1 = Bp0 + 64 * 64;

    f32x4 acc0 = {0.f, 0.f, 0.f, 0.f};
    f32x4 acc1 = {0.f, 0.f, 0.f, 0.f};
#pragma unroll 8
    for (int kt = 0; kt < 64; ++kt) {
        bf16x8 a  = Ap[kt << 6];
        bf16x8 b0 = Bp0[kt << 6];
        bf16x8 b1 = Bp1[kt << 6];
        acc0 = __builtin_amdgcn_mfma_f32_16x16x32_bf16(a, b0, acc0, 0, 0, 0);
        acc1 = __builtin_amdgcn_mfma_f32_16x16x32_bf16(a, b1, acc1, 0, 0, 0);
    }

    // Epilogue: C/D layout col(u)=lane&15, row(b)=(lane>>4)*4+reg.
    const int b0r = (bt << 4) + ((lane >> 4) << 2);
    const int ucol = lane & 15;

    float xv[4][I_];
#pragma unroll
    for (int r = 0; r < 4; ++r) {
        const float* xr = x + ((b0r + r) * T_ + t) * I_;
#pragma unroll
        for (int j = 0; j < I_; ++j) xv[r][j] = xr[j];
    }

#pragma unroll
    for (int i = 0; i < 2; ++i) {
        const f32x4 acc = i ? acc1 : acc0;
        const int u = ((ut0 + i) << 4) + ucol;
        float wv[I_];
#pragma unroll
        for (int j = 0; j < I_; ++j) wv[j] = Win[u * I_ + j];
        const int kt2 = u >> 5;
        const int lane2q = ((u >> 3) & 3) << 4;
        const int jj = u & 7;
#pragma unroll
        for (int r = 0; r < 4; ++r) {
            const int b = b0r + r;
            float it = 0.f;
#pragma unroll
            for (int j = 0; j < I_; ++j) it += xv[r][j] * wv[j];
            float pre = acc[r] + it + noise[(t * B_ + b) * H_ + u];
            float relu = pre > 0.f ? pre : 0.f;
            float hold = hstate[b * H_ + u];
            float hnew = 0.1f * relu + 0.9f * hold;
            hstate[b * H_ + u] = hnew;
            hid_out[(b * T_ + t) * H_ + u] = hnew;
            // re-swizzle into next step's A-frag layout
            hdst[((((bt << 6) + kt2) << 6) + lane2q + (b & 15)) * 8 + jj] = f2bf(hnew);
        }
    }
}

// Output pass: out[b,t,:] = softmax(h[b,t,:] @ Wout^T). One wave per (b,t).
__global__ __launch_bounds__(256) void out_kernel(
    const float* __restrict__ hid,
    const float* __restrict__ Wout,
    float* __restrict__ outp)
{
    const int lane = threadIdx.x & 63;
    const int w = threadIdx.x >> 6;
    const int p = blockIdx.x * 4 + w;          // flattened b*T + t
    const float* hrow = hid + (size_t)p * H_;
    float s0 = 0.f, s1 = 0.f, s2 = 0.f, s3 = 0.f;
#pragma unroll 4
    for (int k = lane; k < H_; k += 64) {
        float hv = hrow[k];
        s0 += hv * Wout[k];
        s1 += hv * Wout[H_ + k];
        s2 += hv * Wout[2 * H_ + k];
        s3 += hv * Wout[3 * H_ + k];
    }
#pragma unroll
    for (int off = 32; off > 0; off >>= 1) {
        s0 += __shfl_down(s0, off);
        s1 += __shfl_down(s1, off);
        s2 += __shfl_down(s2, off);
        s3 += __shfl_down(s3, off);
    }
    if (lane == 0) {
        float m = fmaxf(fmaxf(s0, s1), fmaxf(s2, s3));
        float e0 = __expf(s0 - m), e1 = __expf(s1 - m);
        float e2 = __expf(s2 - m), e3 = __expf(s3 - m);
        float inv = 1.f / (e0 + e1 + e2 + e3);
        float* o = outp + (size_t)p * 4;
        o[0] = e0 * inv; o[1] = e1 * inv; o[2] = e2 * inv; o[3] = e3 * inv;
    }
}

extern "C" void kernel_launch(void* const* d_in, const int* in_sizes, int n_in,
                              void* d_out, int out_size, void* d_ws, size_t ws_size,
                              hipStream_t stream) {
    const float* x     = (const float*)d_in[0];   // [B,T,I]
    const float* Win   = (const float*)d_in[1];   // [H,I]
    const float* Wrec  = (const float*)d_in[2];   // [H,H]
    const float* Wout  = (const float*)d_in[3];   // [O,H]
    const float* noise = (const float*)d_in[4];   // [T,B,H]

    float* hiddens = (float*)d_out;                       // B*T*H
    float* outputs = hiddens + (size_t)B_ * T_ * H_;      // B*T*O

    char* ws = (char*)d_ws;
    unsigned short* Wt  = (unsigned short*)ws;                     // 8 MB
    unsigned short* hA0 = (unsigned short*)(ws + (8u << 20));      // 1 MB
    unsigned short* hA1 = (unsigned short*)(ws + (9u << 20));      // 1 MB
    float* hstate       = (float*)(ws + (10u << 20));              // 2 MB

    hipMemsetAsync(hA0, 0, 1u << 20, stream);      // h_{-1} = 0 (bf16 frags)
    hipMemsetAsync(hstate, 0, 2u << 20, stream);   // h fp32 state = 0

    swizzle_W<<<H_, 256, 0, stream>>>(Wrec, Wt);

    dim3 grid(32, 8);
    for (int t = 0; t < T_; ++t) {
        const unsigned short* src = (t & 1) ? hA1 : hA0;
        unsigned short* dst       = (t & 1) ? hA0 : hA1;
        step_kernel<<<grid, 256, 0, stream>>>(Wt, src, dst, hstate,
                                              x, Win, noise, hiddens, t);
    }

    out_kernel<<<(B_ * T_) / 4, 256, 0, stream>>>(hiddens, Wout, outputs);
}